// Round 1
// baseline (15.237 us; speedup 1.0000x reference)
//
#include <hip/hip_runtime.h>

#define FEAT 2048
#define NUM_DISTORT 24
#define NBASE 1536   // 64 * 24

__global__ __launch_bounds__(256) void hinge_partial(const float* __restrict__ in,
                                                     float* __restrict__ partial) {
    const int bidx  = blockIdx.x;            // 0..1535
    const int batch = bidx / NUM_DISTORT;
    const int dist  = bidx - batch * NUM_DISTORT;
    const long base = (long)batch * dist;    // faithful: batch * distort (multiplication)
    const float* p  = in + base * FEAT;
    const int t = threadIdx.x;

    float acc = 0.f;
    #pragma unroll
    for (int g = 0; g < 2; ++g) {
        const int col = g * 1024 + t * 4;
        float4 x[5];
        #pragma unroll
        for (int l = 0; l < 5; ++l)
            x[l] = *(const float4*)(p + l * FEAT + col);
        #pragma unroll
        for (int i = 0; i < 4; ++i) {
            #pragma unroll
            for (int j = i + 1; j < 5; ++j) {
                acc += fmaxf(x[i].x - x[j].x, 0.f);
                acc += fmaxf(x[i].y - x[j].y, 0.f);
                acc += fmaxf(x[i].z - x[j].z, 0.f);
                acc += fmaxf(x[i].w - x[j].w, 0.f);
            }
        }
    }

    // wave (64-lane) shuffle reduce
    #pragma unroll
    for (int off = 32; off > 0; off >>= 1)
        acc += __shfl_down(acc, off, 64);

    __shared__ float ws[4];
    const int lane = t & 63, wave = t >> 6;
    if (lane == 0) ws[wave] = acc;
    __syncthreads();
    if (t == 0) partial[bidx] = (ws[0] + ws[1]) + (ws[2] + ws[3]);
}

__global__ __launch_bounds__(256) void reduce_final(const float* __restrict__ partial,
                                                    float* __restrict__ out) {
    const int t = threadIdx.x;
    float acc = 0.f;
    #pragma unroll
    for (int i = t; i < NBASE; i += 256) acc += partial[i];

    #pragma unroll
    for (int off = 32; off > 0; off >>= 1)
        acc += __shfl_down(acc, off, 64);

    __shared__ float ws[4];
    const int lane = t & 63, wave = t >> 6;
    if (lane == 0) ws[wave] = acc;
    __syncthreads();
    if (t == 0) out[0] = (ws[0] + ws[1]) + (ws[2] + ws[3]);
}

extern "C" void kernel_launch(void* const* d_in, const int* in_sizes, int n_in,
                              void* d_out, int out_size, void* d_ws, size_t ws_size,
                              hipStream_t stream) {
    const float* in  = (const float*)d_in[0];
    float* out       = (float*)d_out;
    float* partial   = (float*)d_ws;   // 1536 floats = 6 KiB

    hinge_partial<<<NBASE, 256, 0, stream>>>(in, partial);
    reduce_final<<<1, 256, 0, stream>>>(partial, out);
}

// Round 2
// 11.552 us; speedup vs baseline: 1.3189x; 1.3189x over previous
//
#include <hip/hip_runtime.h>

#define FEAT 2048

// Compile-time dedup of base = batch * distort (batch<64, distort<24).
// Result = sum over distinct bases of count(base) * f(base).
struct Table {
    int n;
    short base[1450];
    float cnt[1450];
};

constexpr Table make_table() {
    Table t{};
    int c[1450] = {};
    for (int b = 0; b < 64; ++b)
        for (int d = 0; d < 24; ++d)
            c[b * d]++;
    t.n = 0;
    for (int v = 0; v < 1450; ++v) {
        if (c[v]) {
            t.base[t.n] = (short)v;
            t.cnt[t.n]  = (float)c[v];
            ++t.n;
        }
    }
    return t;
}

constexpr Table TBL = make_table();
constexpr int NDIST = TBL.n;

__constant__ Table d_tbl = make_table();

__global__ __launch_bounds__(256) void hinge_partial(const float* __restrict__ in,
                                                     float* __restrict__ partial) {
    const int bidx = blockIdx.x;              // 0..NDIST-1
    const int base = d_tbl.base[bidx];
    const float w  = d_tbl.cnt[bidx];
    const float* p = in + (long)base * FEAT;
    const int t = threadIdx.x;

    float acc = 0.f;
    #pragma unroll
    for (int g = 0; g < 2; ++g) {
        const int col = g * 1024 + t * 4;
        float4 x[5];
        #pragma unroll
        for (int l = 0; l < 5; ++l)
            x[l] = *(const float4*)(p + l * FEAT + col);
        #pragma unroll
        for (int i = 0; i < 4; ++i) {
            #pragma unroll
            for (int j = i + 1; j < 5; ++j) {
                acc += fmaxf(x[i].x - x[j].x, 0.f);
                acc += fmaxf(x[i].y - x[j].y, 0.f);
                acc += fmaxf(x[i].z - x[j].z, 0.f);
                acc += fmaxf(x[i].w - x[j].w, 0.f);
            }
        }
    }

    // wave (64-lane) shuffle reduce
    #pragma unroll
    for (int off = 32; off > 0; off >>= 1)
        acc += __shfl_down(acc, off, 64);

    __shared__ float ws[4];
    const int lane = t & 63, wave = t >> 6;
    if (lane == 0) ws[wave] = acc;
    __syncthreads();
    if (t == 0) partial[bidx] = w * ((ws[0] + ws[1]) + (ws[2] + ws[3]));
}

__global__ __launch_bounds__(256) void reduce_final(const float* __restrict__ partial,
                                                    float* __restrict__ out) {
    const int t = threadIdx.x;
    float acc = 0.f;
    for (int i = t; i < NDIST; i += 256) acc += partial[i];

    #pragma unroll
    for (int off = 32; off > 0; off >>= 1)
        acc += __shfl_down(acc, off, 64);

    __shared__ float ws[4];
    const int lane = t & 63, wave = t >> 6;
    if (lane == 0) ws[wave] = acc;
    __syncthreads();
    if (t == 0) out[0] = (ws[0] + ws[1]) + (ws[2] + ws[3]);
}

extern "C" void kernel_launch(void* const* d_in, const int* in_sizes, int n_in,
                              void* d_out, int out_size, void* d_ws, size_t ws_size,
                              hipStream_t stream) {
    const float* in  = (const float*)d_in[0];
    float* out       = (float*)d_out;
    float* partial   = (float*)d_ws;   // NDIST floats (< 6 KiB)

    hinge_partial<<<NDIST, 256, 0, stream>>>(in, partial);
    reduce_final<<<1, 256, 0, stream>>>(partial, out);
}

// Round 3
// 10.965 us; speedup vs baseline: 1.3896x; 1.0536x over previous
//
#include <hip/hip_runtime.h>

#define FEAT 2048
#define CH 16            // output rows per chunk
#define COLSPLIT 4
#define THREADS 128      // 128 threads * 4 floats = 512 = FEAT/COLSPLIT

// Reformulation: total = sum_r sum_{delta=1..4} W(r,delta) * g(r, r+delta),
// g(r,s) = sum_feat relu(x_r - x_s), W(r,delta) = sum_{i=0}^{4-delta} cnt[r-i],
// cnt[v] = multiplicity of base value v = batch*distort (batch<64, distort<24).
struct Tables {
    int nchunk;
    short r0[1456];
    float W[1472][4];
};

constexpr Tables make_tables() {
    Tables t{};
    int cnt[1450] = {};
    for (int b = 0; b < 64; ++b)
        for (int d = 0; d < 24; ++d)
            cnt[b * d]++;
    for (int r = 0; r < 1472; ++r)
        for (int dl = 1; dl <= 4; ++dl) {
            int s = 0;
            for (int i = 0; i <= 4 - dl; ++i) {
                int v = r - i;
                if (v >= 0 && v < 1450) s += cnt[v];
            }
            t.W[r][dl - 1] = (float)s;
        }
    // greedy chunking over active rows (active iff W(r,1)>0 iff a base in [r-3,r])
    t.nchunk = 0;
    int r = 0;
    while (r < 1453) {
        bool act = false;
        for (int i = 0; i <= 3; ++i) {
            int v = r - i;
            if (v >= 0 && v < 1450 && cnt[v] > 0) act = true;
        }
        if (act) { t.r0[t.nchunk++] = (short)r; r += CH; }
        else ++r;
    }
    return t;
}

constexpr Tables TBL = make_tables();
constexpr int NCHUNK = TBL.nchunk;
constexpr int NPART  = NCHUNK * COLSPLIT;

__constant__ Tables d_tbl = make_tables();

__global__ __launch_bounds__(THREADS) void hinge_rows(const float* __restrict__ in,
                                                      float* __restrict__ partial) {
    const int chunk = blockIdx.x / COLSPLIT;
    const int chalf = blockIdx.x % COLSPLIT;
    const int r0    = d_tbl.r0[chunk];
    const float* p  = in + (long)r0 * FEAT + chalf * (FEAT / COLSPLIT) + threadIdx.x * 4;

    float4 x[5];
    #pragma unroll
    for (int l = 0; l < 4; ++l)
        x[l] = *(const float4*)(p + l * FEAT);

    float acc0 = 0.f, acc1 = 0.f;
    #pragma unroll
    for (int k = 0; k < CH; ++k) {
        x[4] = *(const float4*)(p + (k + 4) * FEAT);
        #pragma unroll
        for (int dl = 1; dl <= 4; ++dl) {
            const float w = d_tbl.W[r0 + k][dl - 1];
            float s = fmaxf(x[0].x - x[dl].x, 0.f)
                    + fmaxf(x[0].y - x[dl].y, 0.f)
                    + fmaxf(x[0].z - x[dl].z, 0.f)
                    + fmaxf(x[0].w - x[dl].w, 0.f);
            if (dl & 1) acc0 = fmaf(w, s, acc0);
            else        acc1 = fmaf(w, s, acc1);
        }
        #pragma unroll
        for (int l = 0; l < 4; ++l) x[l] = x[l + 1];
    }

    float acc = acc0 + acc1;
    #pragma unroll
    for (int off = 32; off > 0; off >>= 1)
        acc += __shfl_down(acc, off, 64);

    __shared__ float ws2[THREADS / 64];
    const int lane = threadIdx.x & 63, wave = threadIdx.x >> 6;
    if (lane == 0) ws2[wave] = acc;
    __syncthreads();
    if (threadIdx.x == 0) partial[blockIdx.x] = ws2[0] + ws2[1];
}

__global__ __launch_bounds__(256) void reduce_final(const float* __restrict__ partial,
                                                    float* __restrict__ out) {
    const int t = threadIdx.x;
    float acc = 0.f;
    for (int i = t; i < NPART; i += 256) acc += partial[i];

    #pragma unroll
    for (int off = 32; off > 0; off >>= 1)
        acc += __shfl_down(acc, off, 64);

    __shared__ float ws[4];
    const int lane = t & 63, wave = t >> 6;
    if (lane == 0) ws[wave] = acc;
    __syncthreads();
    if (t == 0) out[0] = (ws[0] + ws[1]) + (ws[2] + ws[3]);
}

extern "C" void kernel_launch(void* const* d_in, const int* in_sizes, int n_in,
                              void* d_out, int out_size, void* d_ws, size_t ws_size,
                              hipStream_t stream) {
    const float* in  = (const float*)d_in[0];
    float* out       = (float*)d_out;
    float* partial   = (float*)d_ws;   // NPART floats (< 24 KiB)

    hinge_rows<<<NPART, THREADS, 0, stream>>>(in, partial);
    reduce_final<<<1, 256, 0, stream>>>(partial, out);
}